// Round 8
// baseline (288.495 us; speedup 1.0000x reference)
//
#include <hip/hip_runtime.h>

typedef __bf16 bf16_t;
typedef __bf16 bf16x8 __attribute__((ext_vector_type(8)));
typedef float f32x4 __attribute__((ext_vector_type(4)));
typedef unsigned short us4 __attribute__((ext_vector_type(4)));
typedef unsigned short us8 __attribute__((ext_vector_type(8)));
typedef float f4u __attribute__((ext_vector_type(4), aligned(4)));   // dword-aligned float4 load
typedef float f2u __attribute__((ext_vector_type(2), aligned(4)));   // dword-aligned float2 load

#define LO4(v) __builtin_shufflevector(v, v, 0, 1, 2, 3)
#define HI4(v) __builtin_shufflevector(v, v, 4, 5, 6, 7)

// ---------------- foveation ----------------
// glimpse[b, (k*3+c)*1024 + gy*32 + gx] = avgpool_F( x[b,c, st1-pad+gy*F+dy, st0-pad+gx*F+dx] )
// Vectorized row loads (dwordx4/x2, 4B alignment suffices); scalar fallback at image edges.
// Component adds sequenced in ascending dx -> bit-identical to scalar summation order.
template<int F>
__device__ __forceinline__ void fov_scale(const float* __restrict__ xb,
                                          bf16_t* __restrict__ gb,
                                          int r0, int c0, int base, int count, int kidx)
{
  constexpr float inv = 1.0f / (F * F);
  for (int i = threadIdx.x; i < count; i += 256) {
    const int idx = base + i;              // 0..3071 within this scale (c*1024 + gy*32 + gx)
    const int ch  = idx >> 10;
    const int rem = idx & 1023;
    const int gy  = rem >> 5, gx = rem & 31;
    const float* xc = xb + ch * 50176;
    float sum = 0.0f;
    const int rbase = r0 + gy * F, cbase = c0 + gx * F;
    if (cbase >= 0 && cbase + F <= 224) {
      // fast path: all F columns in-bounds -> one vector load per row
#pragma unroll
      for (int dy = 0; dy < F; ++dy) {
        const int rr = rbase + dy;
        if ((unsigned)rr < 224u) {
          const float* p = xc + rr * 224 + cbase;
          if constexpr (F == 4) {
            const f4u v = *(const f4u*)p;
            sum += v[0]; sum += v[1]; sum += v[2]; sum += v[3];
          } else if constexpr (F == 2) {
            const f2u v = *(const f2u*)p;
            sum += v[0]; sum += v[1];
          } else {
            sum += p[0];
          }
        }
      }
    } else {
      // edge path: per-column bounds checks (identical to reference zero-pad semantics)
#pragma unroll
      for (int dy = 0; dy < F; ++dy) {
        const int rr = rbase + dy;
        if ((unsigned)rr < 224u) {
#pragma unroll
          for (int dx = 0; dx < F; ++dx) {
            const int cc = cbase + dx;
            if ((unsigned)cc < 224u) sum += xc[rr * 224 + cc];
          }
        }
      }
    }
    gb[kidx * 3072 + idx] = (bf16_t)(sum * inv);
  }
}

__device__ __forceinline__ void fov_unit(const float* __restrict__ x,
                                         const float* __restrict__ l,
                                         bf16_t* __restrict__ g, int u)
{
  const int b = u & 255;
  const int y = u >> 8;       // 7 work partitions
  const float l0 = l[2 * b], l1 = l[2 * b + 1];
  // match reference exactly: (int)(0.5f * ((l + 1.0f) * 224.0f)), trunc (values >= 0)
  const int st0 = (int)(0.5f * ((l0 + 1.0f) * 224.0f));  // col start
  const int st1 = (int)(0.5f * ((l1 + 1.0f) * 224.0f));  // row start
  const float* xb = x + (size_t)b * 3 * 50176;
  bf16_t* gb = g + (size_t)b * 9216;
  if (y == 0) {
    fov_scale<1>(xb, gb, st1 - 17, st0 - 17, 0, 3072, 0);              // pad = 32/2+1
  } else if (y <= 2) {
    fov_scale<2>(xb, gb, st1 - 33, st0 - 33, (y - 1) * 1536, 1536, 1); // pad = 64/2+1
  } else {
    fov_scale<4>(xb, gb, st1 - 65, st0 - 65, (y - 3) * 768, 768, 2);   // pad = 128/2+1
  }
}

// ---------------- 64x64 fp32 -> bf16 transpose tile (float4 reads) ----------------
// src: tile origin of [64 k][64 n] fp32, row stride srcld (multiple of 4).
// dst: tile origin of [64 n][64 k] bf16 (as ushort), row stride dstld.
__device__ __forceinline__ void transpose_tile(const float* __restrict__ src, int srcld,
                                               unsigned short* __restrict__ dst, int dstld,
                                               unsigned short* __restrict__ T)
{
  const int t = threadIdx.x;
#pragma unroll
  for (int it = 0; it < 4; ++it) {
    const int lin = it * 256 + t;             // 0..1023 float4-quads
    const int kk = lin >> 4, nn = (lin & 15) * 4;   // coalesced f4 along nn
    const float4 v = *(const float4*)(src + (size_t)kk * srcld + nn);
    T[(nn + 0) * 72 + kk] = __builtin_bit_cast(unsigned short, (bf16_t)v.x);
    T[(nn + 1) * 72 + kk] = __builtin_bit_cast(unsigned short, (bf16_t)v.y);
    T[(nn + 2) * 72 + kk] = __builtin_bit_cast(unsigned short, (bf16_t)v.z);
    T[(nn + 3) * 72 + kk] = __builtin_bit_cast(unsigned short, (bf16_t)v.w);
  }
  __syncthreads();
#pragma unroll
  for (int it = 0; it < 2; ++it) {
    const int q = it * 256 + t;          // 0..511
    const int n = q >> 3, kc = (q & 7) * 8;
    *(us8*)(dst + (size_t)n * dstld + kc) = *(const us8*)&T[n * 72 + kc];
  }
}

// ---------------- kernel 1: foveate (1792) + weight transpose/convert (3328) ----------------
__global__ __launch_bounds__(256) void fov_conv_kernel(const float* __restrict__ x,
                                                       const float* __restrict__ l,
                                                       bf16_t* __restrict__ g,
                                                       const float* __restrict__ W1,
                                                       const float* __restrict__ W3,
                                                       const float* __restrict__ W4,
                                                       bf16_t* __restrict__ W1t,
                                                       bf16_t* __restrict__ W34t)
{
  __shared__ unsigned short T[64 * 72];
  const int bid = blockIdx.x;
  if (bid < 1792) {
    fov_unit(x, l, g, bid);
  } else if (bid < 4096) {
    const int cid = bid - 1792;          // 144 ktiles x 16 ntiles
    const int kt = cid >> 4, nt = cid & 15;
    transpose_tile(W1 + (size_t)(kt * 64) * 1024 + nt * 64, 1024,
                   (unsigned short*)W1t + (size_t)(nt * 64) * 9216 + kt * 64, 9216, T);
  } else {
    const int cid = bid - 4096;          // 32 ktiles x 32 ntiles
    const int kt = cid >> 5, nt = cid & 31;
    const int k0 = kt * 64;              // tile never straddles k=1024 (64 | 1024)
    const float* src = (k0 < 1024) ? (W3 + (size_t)k0 * 2048 + nt * 64)
                                   : (W4 + (size_t)(k0 - 1024) * 2048 + nt * 64);
    transpose_tile(src, 2048,
                   (unsigned short*)W34t + (size_t)(nt * 64) * 2048 + k0, 2048, T);
  }
}

// ---------------- split-K bf16 MFMA GEMM (both operands k-contiguous bf16) ----------------
template<int BM, int BN, int KCHUNK, int NDIM, int KFULL>
__global__ __launch_bounds__(256) void gemm_bb(const bf16_t* __restrict__ A,
                                               const bf16_t* __restrict__ Bt,
                                               float* __restrict__ part)
{
  constexpr int WROWS = BM / 4;     // rows per wave
  constexpr int SM = WROWS / 16;    // 16-row subtiles per wave
  constexpr int SN = BN / 16;       // 16-col subtiles
  constexpr int LDA = 36;           // LDS row stride (ushorts): conflict-benign for b64 frag reads
  constexpr int NLA = BM / 64;      // us8 A loads per thread per k-step
  __shared__ unsigned short Al[BM * LDA];
  __shared__ unsigned short Bl[BN * LDA];
  const int t = threadIdx.x;
  const int w = t >> 6, lane = t & 63;
  const int lr = lane & 15, kg = lane >> 4;
  const int bm0 = blockIdx.x * BM, bn0 = blockIdx.y * BN;
  const int ks0 = blockIdx.z * KCHUNK;
  const unsigned short* Au = (const unsigned short*)A;
  const unsigned short* Bu = (const unsigned short*)Bt;

  const int bn = t >> 2, bkb = (t & 3) * 8;
  const bool bld = (t < BN * 4);    // wave-uniform (multiple-of-64 cut)

  f32x4 acc[SM][SN] = {};
  us8 pa[NLA], pb;

  // prologue: load k-tile 0 into regs
#pragma unroll
  for (int i = 0; i < NLA; ++i) {
    const int q = t + 256 * i;
    pa[i] = *(const us8*)(Au + (size_t)(bm0 + (q >> 2)) * KFULL + ks0 + (q & 3) * 8);
  }
  if (bld) pb = *(const us8*)(Bu + (size_t)(bn0 + bn) * KFULL + ks0 + bkb);

  for (int k0 = 0; k0 < KCHUNK; k0 += 32) {
    // ---- regs -> LDS ----
#pragma unroll
    for (int i = 0; i < NLA; ++i) {
      const int q = t + 256 * i;
      const int m = q >> 2, kb = (q & 3) * 8;
      *(us4*)(&Al[m * LDA + kb])     = LO4(pa[i]);
      *(us4*)(&Al[m * LDA + kb + 4]) = HI4(pa[i]);
    }
    if (bld) {
      *(us4*)(&Bl[bn * LDA + bkb])     = LO4(pb);
      *(us4*)(&Bl[bn * LDA + bkb + 4]) = HI4(pb);
    }
    __syncthreads();
    // ---- prefetch next k-tile into regs (overlaps with frag reads + MFMA) ----
    if (k0 + 32 < KCHUNK) {
      const int knext = ks0 + k0 + 32;
#pragma unroll
      for (int i = 0; i < NLA; ++i) {
        const int q = t + 256 * i;
        pa[i] = *(const us8*)(Au + (size_t)(bm0 + (q >> 2)) * KFULL + knext + (q & 3) * 8);
      }
      if (bld) pb = *(const us8*)(Bu + (size_t)(bn0 + bn) * KFULL + knext + bkb);
    }
    // ---- fragments (A[m=lr][k=kg*8+j], B[n=lr][k=kg*8+j]) + MFMA ----
    bf16x8 af[SM], bfr[SN];
#pragma unroll
    for (int sm = 0; sm < SM; ++sm) {
      const unsigned short* p = &Al[(w * WROWS + sm * 16 + lr) * LDA + kg * 8];
      us4 x0 = *(const us4*)p;
      us4 x1 = *(const us4*)(p + 4);
      af[sm] = __builtin_bit_cast(bf16x8, __builtin_shufflevector(x0, x1, 0, 1, 2, 3, 4, 5, 6, 7));
    }
#pragma unroll
    for (int sn = 0; sn < SN; ++sn) {
      const unsigned short* p = &Bl[(sn * 16 + lr) * LDA + kg * 8];
      us4 x0 = *(const us4*)p;
      us4 x1 = *(const us4*)(p + 4);
      bfr[sn] = __builtin_bit_cast(bf16x8, __builtin_shufflevector(x0, x1, 0, 1, 2, 3, 4, 5, 6, 7));
    }
#pragma unroll
    for (int sm = 0; sm < SM; ++sm)
#pragma unroll
      for (int sn = 0; sn < SN; ++sn)
        acc[sm][sn] = __builtin_amdgcn_mfma_f32_16x16x32_bf16(af[sm], bfr[sn], acc[sm][sn], 0, 0, 0);
    __syncthreads();
  }
  // ---- write fp32 partials (C/D layout: col=lr, row=kg*4+r) ----
  float* outp = part + (size_t)blockIdx.z * ((size_t)256 * NDIM);
#pragma unroll
  for (int sm = 0; sm < SM; ++sm)
#pragma unroll
    for (int sn = 0; sn < SN; ++sn)
#pragma unroll
      for (int r = 0; r < 4; ++r) {
        const int gm = bm0 + w * WROWS + sm * 16 + kg * 4 + r;
        const int gn = bn0 + sn * 16 + lr;
        outp[(size_t)gm * NDIM + gn] = acc[sm][sn][r];
      }
}

// ---------------- reduce GEMM1 partials (16) + bias + relu -> bf16; also l_out path ----------------
// float4-vectorized: 4 cols/thread, 512 blocks. Same summation order as scalar version.
__global__ __launch_bounds__(256) void fuse_mid(const float* __restrict__ part1,
                                                const float* __restrict__ b1,
                                                const float* __restrict__ lprev,
                                                const float* __restrict__ W2,
                                                const float* __restrict__ b2,
                                                bf16_t* __restrict__ A2)
{
  const int q = blockIdx.x * 256 + threadIdx.x;  // 0..131071
  const int row = q >> 9, c4 = (q & 511) * 4;    // block-uniform branch (c4 chunk of 1024)
  float4 s;
  if (c4 < 1024) {
    s = *(const float4*)(b1 + c4);
#pragma unroll
    for (int i = 0; i < 16; ++i) {
      const float4 p = *(const float4*)(part1 + i * 262144 + row * 1024 + c4);
      s.x += p.x; s.y += p.y; s.z += p.z; s.w += p.w;
    }
  } else {
    const int n = c4 - 1024;
    const float a0 = lprev[2 * row], a1 = lprev[2 * row + 1];
    const float4 w0 = *(const float4*)(W2 + n);
    const float4 w1 = *(const float4*)(W2 + 1024 + n);
    const float4 bb = *(const float4*)(b2 + n);
    s.x = fmaf(a0, w0.x, fmaf(a1, w1.x, bb.x));
    s.y = fmaf(a0, w0.y, fmaf(a1, w1.y, bb.y));
    s.z = fmaf(a0, w0.z, fmaf(a1, w1.z, bb.z));
    s.w = fmaf(a0, w0.w, fmaf(a1, w1.w, bb.w));
  }
  us4 o;
  o[0] = __builtin_bit_cast(unsigned short, (bf16_t)fmaxf(s.x, 0.0f));
  o[1] = __builtin_bit_cast(unsigned short, (bf16_t)fmaxf(s.y, 0.0f));
  o[2] = __builtin_bit_cast(unsigned short, (bf16_t)fmaxf(s.z, 0.0f));
  o[3] = __builtin_bit_cast(unsigned short, (bf16_t)fmaxf(s.w, 0.0f));
  *(us4*)((unsigned short*)A2 + (size_t)row * 2048 + c4) = o;
}

// ---------------- reduce GEMM2 partials (8) + (b3+b4) + relu -> fp32 out (float4) ----------------
__global__ __launch_bounds__(256) void epilogue2(const float* __restrict__ part2,
                                                 const float* __restrict__ b3,
                                                 const float* __restrict__ b4,
                                                 float* __restrict__ out)
{
  const int q = blockIdx.x * 256 + threadIdx.x;  // 0..131071
  const int c4 = (q & 511) * 4;
  const float4 v3 = *(const float4*)(b3 + c4);
  const float4 v4 = *(const float4*)(b4 + c4);
  float4 s = make_float4(v3.x + v4.x, v3.y + v4.y, v3.z + v4.z, v3.w + v4.w);
#pragma unroll
  for (int i = 0; i < 8; ++i) {
    const float4 p = *(const float4*)(part2 + i * 524288 + q * 4);
    s.x += p.x; s.y += p.y; s.z += p.z; s.w += p.w;
  }
  s.x = fmaxf(s.x, 0.0f); s.y = fmaxf(s.y, 0.0f);
  s.z = fmaxf(s.z, 0.0f); s.w = fmaxf(s.w, 0.0f);
  *(float4*)(out + (size_t)q * 4) = s;
}

extern "C" void kernel_launch(void* const* d_in, const int* in_sizes, int n_in,
                              void* d_out, int out_size, void* d_ws, size_t ws_size,
                              hipStream_t stream)
{
  const float* x     = (const float*)d_in[0];
  const float* lprev = (const float*)d_in[1];
  const float* W1    = (const float*)d_in[2];   // (9216, 1024)
  const float* b1    = (const float*)d_in[3];
  const float* W2    = (const float*)d_in[4];   // (2, 1024)
  const float* b2    = (const float*)d_in[5];
  const float* W3    = (const float*)d_in[6];   // (1024, 2048)
  const float* b3    = (const float*)d_in[7];
  const float* W4    = (const float*)d_in[8];   // (1024, 2048)
  const float* b4    = (const float*)d_in[9];
  float* out = (float*)d_out;

  // workspace layout (all 16B aligned), total ~66.6 MB
  char* ws = (char*)d_ws;
  bf16_t* glimpse = (bf16_t*)ws;                 // 256*9216*2    =  4,718,592 B
  bf16_t* A2      = (bf16_t*)(ws + 4718592);     // 256*2048*2    =  1,048,576 B
  float*  part1   = (float*)(ws + 5767168);      // 16*256*1024*4 = 16,777,216 B
  float*  part2   = (float*)(ws + 22544384);     // 8*256*2048*4  = 16,777,216 B
  bf16_t* W1t     = (bf16_t*)(ws + 39321600);    // 1024*9216*2   = 18,874,368 B
  bf16_t* W34t    = (bf16_t*)(ws + 58195968);    // 2048*2048*2   =  8,388,608 B

  // kernel 1: foveation (1792) + W1 transpose (2304) + W34 transpose (1024)
  fov_conv_kernel<<<5120, 256, 0, stream>>>(x, lprev, glimpse, W1, W3, W4, W1t, W34t);
  // kernel 2: GEMM1 M=256,N=1024,K=9216; 128x64 tiles, splitK=16 -> 512 blocks (2/CU)
  gemm_bb<128, 64, 576, 1024, 9216>
      <<<dim3(2, 16, 16), 256, 0, stream>>>(glimpse, W1t, part1);
  // kernel 3: reduce + bias + relu -> A2 (float4, 512 blocks)
  fuse_mid<<<512, 256, 0, stream>>>(part1, b1, lprev, W2, b2, A2);
  // kernel 4: GEMM2 M=256,N=2048,K=2048; 128x64 tiles, splitK=8 -> 512 blocks
  gemm_bb<128, 64, 256, 2048, 2048>
      <<<dim3(2, 32, 8), 256, 0, stream>>>(A2, W34t, part2);
  // kernel 5: reduce + (b3+b4) + relu -> out (float4, 512 blocks)
  epilogue2<<<512, 256, 0, stream>>>(part2, b3, b4, out);
}